// Round 20
// baseline (105.585 us; speedup 1.0000x reference)
//
#include <hip/hip_runtime.h>
#include <hip/hip_bf16.h>
#include <math.h>

// ---------------------------------------------------------------------------
// GatedTinyMambaLayer: B=8, T=2048, DM=1024, DS=256
// Pipeline: cvt_x (R3-exact: 16384 blk x 4 elem/thread) -> prep_ws ->
// gemm1sg (128x192, BK=64, 1 barrier/K-tile, fused S,G) -> gemm2h -> gemm3.
// wcat: 4 groups of 192 rows: {W_in+W_x[g*64..], W_gx[g*64..], W_dc[g*64..]}.
// R20 journal: 8-elem/thread cvt variants (R5..R19, strided AND contiguous)
// all ~36-40us (~2.5TB/s); R3's 4-elem/thread form measured ~20us. Single-
// variable revert to R3-exact to isolate.
// ---------------------------------------------------------------------------

typedef __attribute__((ext_vector_type(4)))  float f32x4;
typedef __attribute__((ext_vector_type(8)))  short bf16x8;

#define DEV static __device__ __forceinline__

DEV float bf2f(short u) {
  union { float f; unsigned i; } v; v.i = ((unsigned)(unsigned short)u) << 16; return v.f;
}
DEV short f2bf(float f) {  // round-to-nearest-even
  union { float f; unsigned i; } v; v.f = f;
  unsigned x = v.i;
  return (short)((x + 0x7fffu + ((x >> 16) & 1u)) >> 16);
}
DEV unsigned pk_bf16(float lo, float hi) {  // -> v_cvt_pk_bf16_f32
  __hip_bfloat162 h = __float22bfloat162_rn(make_float2(lo, hi));
  return *(unsigned*)&h;
}
DEV float sigmoidf_(float x) { return 1.f / (1.f + expf(-x)); }

DEV void gl16(const void* g, void* l) {
  __builtin_amdgcn_global_load_lds(
      (const __attribute__((address_space(1))) void*)(g),
      (__attribute__((address_space(3))) void*)(l), 16, 0, 0);
}

// ---- workspace layout (bytes) ---------------------------------------------
static const size_t OFF_S    = 0;                   // bf16 [16384][256]
static const size_t OFF_G    = 8388608;             // bf16 [16384][256]
static const size_t OFF_XBF  = 25165824;            // bf16 [16384][1024]; H aliases (dead after gemm1)
static const size_t OFF_WCAT = OFF_XBF + 33554432;  // bf16 [768][1024] (192-row groups)
static const size_t OFF_WPP  = OFF_WCAT + 1572864;  // bf16 [256][256]  (W_pp[:, :256])
static const size_t OFF_WOUT = OFF_WPP + 131072;    // bf16 [1024][256]
static const size_t OFF_VEC  = OFF_WOUT + 524288;   // f32 [5][2048]: sdc,sws,spp,pstr,gst

// ---------------------------------------------------------------------------
// cvt_x: R3-exact form. 16384 blocks x 256 thr x 4 elems.
__global__ __launch_bounds__(256, 1) void cvt_x_k(const float* __restrict__ x,
                                                  short* __restrict__ xbf) {
  const size_t i = ((size_t)blockIdx.x * 256 + threadIdx.x) * 4;
  const float4 v = *(const float4*)(x + i);
  short4 o;
  o.x = f2bf(v.x); o.y = f2bf(v.y); o.z = f2bf(v.z); o.w = f2bf(v.w);
  *(short4*)(xbf + i) = o;
}

// ---------------------------------------------------------------------------
// prep_ws: blocks [0,4352) weight prep ; [4352,4512) state GEMVs
__global__ __launch_bounds__(256, 1) void prep_ws_k(
    const float* __restrict__ W_in, const float* __restrict__ W_x,
    const float* __restrict__ W_gx, const float* __restrict__ W_dc,
    const float* __restrict__ W_pp, const float* __restrict__ W_out,
    short* __restrict__ wcat, short* __restrict__ wpp, short* __restrict__ wout,
    const float* __restrict__ prev, const float* __restrict__ Ws,
    const float* __restrict__ bdc, const float* __restrict__ bpp,
    const float* __restrict__ Wpg, const float* __restrict__ bpg,
    const float* __restrict__ Wgs, const float* __restrict__ bgs,
    float* __restrict__ vecs) {
  const int bid = (int)blockIdx.x, tid = (int)threadIdx.x;
  if (bid < 4352) {  // ---- weight prep (192-row groups)
    const int idx = bid * 256 + tid;
    const int N_WCAT = 768 * 1024, N_WPP = 256 * 256;
    if (idx < N_WCAT) {
      const int r = idx >> 10, k = idx & 1023;
      const int g = r / 192, j = r % 192;
      float v;
      if (j < 64)       v = W_in[(g * 64 + j) * 1024 + k] + W_x[(g * 64 + j) * 1024 + k];
      else if (j < 128) v = W_gx[(g * 64 + j - 64) * 1024 + k];
      else              v = W_dc[(g * 64 + j - 128) * 1280 + k];
      wcat[idx] = f2bf(v);
    } else if (idx < N_WCAT + N_WPP) {
      const int j = idx - N_WCAT, o = j >> 8, k = j & 255;
      wpp[j] = f2bf(W_pp[o * 512 + k]);          // W_pp[:, :256]
    } else {
      const int j = idx - N_WCAT - N_WPP, o = j >> 8, k = j & 255;
      wout[j] = f2bf(W_out[o * 256 + k]);
    }
  } else {  // ---- per-batch state GEMVs (coalesced, butterfly reduce)
    const int sb = bid - 4352;
    const int b = sb / 20, rem = sb % 20, m = rem >> 2, oq = rem & 3;
    const int lane = tid & 63, w = tid >> 6;
    const float4 sv = *(const float4*)(prev + b * 256 + lane * 4);
    const float* Wb; const float* bias; int stride, off;
    if (m == 0)      { Wb = W_dc; stride = 1280; off = 1024; bias = bdc; }
    else if (m == 1) { Wb = Ws;   stride = 256;  off = 0;    bias = nullptr; }
    else if (m == 2) { Wb = W_pp; stride = 512;  off = 256;  bias = bpp; }
    else if (m == 3) { Wb = Wpg;  stride = 256;  off = 0;    bias = bpg; }
    else             { Wb = Wgs;  stride = 256;  off = 0;    bias = bgs; }
    const int o0 = oq * 64 + w * 16;
#pragma unroll 4
    for (int i = 0; i < 16; ++i) {
      const int o = o0 + i;
      const float4 wv = *(const float4*)(Wb + (size_t)o * stride + off + lane * 4);
      float p = wv.x * sv.x + wv.y * sv.y + wv.z * sv.z + wv.w * sv.w;
#pragma unroll
      for (int d = 32; d >= 1; d >>= 1) p += __shfl_xor(p, d, 64);
      if (lane == 0) {
        float r = (m == 1) ? 0.5f * p : p + bias[o];
        if (m >= 3) r = sigmoidf_(r);
        vecs[m * 2048 + b * 256 + o] = r;
      }
    }
  }
}

// ---------------------------------------------------------------------------
// GEMM1+SG BK=64: 128x192 tile, 512 threads (8 waves, each 16 rows x 192
// cols, acc[12]). grid = 128 m x 4 grp = 512 blocks (2/CU, 80KB LDS).
// Per K-tile: {stage(t+1) -> A-frag reads -> 3 component phases x 8 MFMA ->
// vmcnt(0) [own stages, issued a tile ago] -> s_barrier}. One barrier/tile.
// Epilogue: S = prev*exp(-.05*sig(dc+sdc)) + ix + sws ; G = sig(gx+bgx).
__global__ __launch_bounds__(512) void gemm1sg_k(const short* __restrict__ A,
                                                 const short* __restrict__ Bm,
                                                 const float* __restrict__ prev,
                                                 const float* __restrict__ bgx,
                                                 const float* __restrict__ vecs,
                                                 short* __restrict__ S,
                                                 short* __restrict__ G) {
  __shared__ short As[2][8192];    // [128][64] dbuf, granule-XOR swizzled
  __shared__ short Bs[2][12288];   // [192][64] dbuf
  const int tid = (int)threadIdx.x, lane = tid & 63, w = tid >> 6;
  int bid = (int)blockIdx.x;
  bid = (bid & 7) * 64 + (bid >> 3);           // XCD swizzle (512 % 8 == 0)
  const int mt = bid >> 2, grp = bid & 3;
  const int m0 = mt * 128, b = m0 >> 11;       // one batch per 128-row tile
  const short* gA = A + (size_t)m0 * 1024;
  const short* gB = Bm + (size_t)(grp * 192) * 1024;

  f32x4 acc[12];
#pragma unroll
  for (int ni = 0; ni < 12; ++ni)
#pragma unroll
    for (int r = 0; r < 4; ++r) acc[ni][r] = 0.f;

#define STGA(buf, t)                                                          \
  {                                                                           \
    _Pragma("unroll")                                                         \
    for (int j = 0; j < 2; ++j) {                                             \
      const int Gr = j * 512 + tid, r = Gr >> 3, g = Gr & 7;                  \
      gl16(gA + (size_t)r * 1024 + (t) * 64 + ((g ^ (r & 7)) * 8),            \
           As[buf] + Gr * 8);                                                 \
    }                                                                         \
  }
#define STGB(buf, t)                                                          \
  {                                                                           \
    _Pragma("unroll")                                                         \
    for (int j = 0; j < 3; ++j) {                                             \
      const int Gr = j * 512 + tid, r = Gr >> 3, g = Gr & 7;                  \
      gl16(gB + (size_t)r * 1024 + (t) * 64 + ((g ^ (r & 7)) * 8),            \
           Bs[buf] + Gr * 8);                                                 \
    }                                                                         \
  }

  STGA(0, 0); STGB(0, 0);
  asm volatile("s_waitcnt vmcnt(0)" ::: "memory");
  __builtin_amdgcn_s_barrier();

  const int arow = lane & 15, ag = lane >> 4;
  const int rowA = w * 16 + arow;
  const int swzA = rowA & 7;
#pragma unroll 1
  for (int t = 0; t < 16; ++t) {
    const short* sA = As[t & 1];
    const short* sB = Bs[t & 1];
    if (t < 15) { STGA((t + 1) & 1, t + 1); STGB((t + 1) & 1, t + 1); }
    bf16x8 af[2];
#pragma unroll
    for (int ks = 0; ks < 2; ++ks)
      af[ks] = *(const bf16x8*)(sA + rowA * 64 + (((ks * 4 + ag) ^ swzA) << 3));
    __builtin_amdgcn_s_setprio(1);
#pragma unroll
    for (int q = 0; q < 3; ++q) {
#pragma unroll
      for (int fj = 0; fj < 4; ++fj) {
        const int r = q * 64 + fj * 16 + arow;
#pragma unroll
        for (int ks = 0; ks < 2; ++ks) {
          const bf16x8 bf = *(const bf16x8*)(sB + r * 64 + (((ks * 4 + ag) ^ (r & 7)) << 3));
          acc[q * 4 + fj] = __builtin_amdgcn_mfma_f32_16x16x32_bf16(
              af[ks], bf, acc[q * 4 + fj], 0, 0, 0);
        }
      }
    }
    __builtin_amdgcn_s_setprio(0);
    if (t < 15) { asm volatile("s_waitcnt vmcnt(0)" ::: "memory"); }
    __builtin_amdgcn_s_barrier();
  }
#undef STGA
#undef STGB

  // epilogue: acc[0-3] = ix, [4-7] = gx, [8-11] = dc for cols grp*64..+63
  const int quad = lane >> 4;
#pragma unroll
  for (int cidx = 0; cidx < 4; ++cidx) {
    const int cg = grp * 64 + cidx * 16 + arow;
    const float sdc = vecs[0 * 2048 + b * 256 + cg];
    const float sws = vecs[1 * 2048 + b * 256 + cg];
    const float pv  = prev[b * 256 + cg];
    const float bg  = bgx[cg];
#pragma unroll
    for (int r = 0; r < 4; ++r) {
      const int row = m0 + w * 16 + quad * 4 + r;
      const float dec = expf(-0.05f * sigmoidf_(acc[8 + cidx][r] + sdc));
      const float sp = pv * dec + acc[cidx][r] + sws;
      const float g = sigmoidf_(acc[4 + cidx][r] + bg);
      S[(size_t)row * 256 + cg] = f2bf(sp);
      G[(size_t)row * 256 + cg] = f2bf(g);
    }
  }
}

// ---------------------------------------------------------------------------
// GEMM2 + elementwise: P = S @ wpp^T; h = (S + pstr*tanh(P+spp)) * G * gst
// 64x128 tile, grid = 256 m x 2 n = 512 blocks (2/CU). Wave = 32r x 64c.
__global__ __launch_bounds__(256) void gemm2h_k(const short* __restrict__ S,
                                                const short* __restrict__ G,
                                                const short* __restrict__ Wpp,
                                                const float* __restrict__ vecs,
                                                short* __restrict__ H,
                                                float* __restrict__ out) {
  __shared__ short As2[2][2048];   // [64][32]
  __shared__ short Bs2[2][4096];   // [128][32]
  const int tid = (int)threadIdx.x, lane = tid & 63, w = tid >> 6;
  const int wr = w >> 1, wc = w & 1;
  int bid = (int)blockIdx.x;
  bid = (bid & 7) * 64 + (bid >> 3);           // XCD swizzle (512 % 8 == 0)
  const int m0 = (bid >> 1) * 64, n0 = (bid & 1) * 128;
  const int b = m0 >> 11;
  const short* gA = S + (size_t)m0 * 256;
  const short* gB = Wpp + (size_t)n0 * 256;

  f32x4 acc[2][4];
#pragma unroll
  for (int mi = 0; mi < 2; ++mi)
#pragma unroll
    for (int ni = 0; ni < 4; ++ni)
#pragma unroll
      for (int r = 0; r < 4; ++r) acc[mi][ni][r] = 0.f;

#define STAGE2(buf, t)                                                        \
  {                                                                           \
    {                                                                         \
      const int g = tid;                                                      \
      gl16(gA + (size_t)(g >> 2) * 256 + (t) * 32 + (g & 3) * 8,              \
           As2[buf] + w * 512);                                               \
    }                                                                         \
    _Pragma("unroll")                                                         \
    for (int j = 0; j < 2; ++j) {                                             \
      const int g = j * 256 + tid;                                            \
      gl16(gB + (size_t)(g >> 2) * 256 + (t) * 32 + (g & 3) * 8,              \
           Bs2[buf] + (j * 256 + w * 64) * 8);                                \
    }                                                                         \
  }

  STAGE2(0, 0);
  __syncthreads();
  const int arow = lane & 15, ag = lane >> 4;
#pragma unroll 1
  for (int t = 0; t < 8; ++t) {
    if (t < 7) STAGE2((t + 1) & 1, t + 1);
    const short* Asb = As2[t & 1];
    const short* Bsb = Bs2[t & 1];
    bf16x8 af[2], bfv[4];
#pragma unroll
    for (int mi = 0; mi < 2; ++mi)
      af[mi] = *(const bf16x8*)(Asb + (wr * 32 + mi * 16 + arow) * 32 + ag * 8);
#pragma unroll
    for (int ni = 0; ni < 4; ++ni)
      bfv[ni] = *(const bf16x8*)(Bsb + (wc * 64 + ni * 16 + arow) * 32 + ag * 8);
#pragma unroll
    for (int mi = 0; mi < 2; ++mi)
#pragma unroll
      for (int ni = 0; ni < 4; ++ni)
        acc[mi][ni] = __builtin_amdgcn_mfma_f32_16x16x32_bf16(af[mi], bfv[ni], acc[mi][ni], 0, 0, 0);
    __syncthreads();
  }
#undef STAGE2

#pragma unroll
  for (int mi = 0; mi < 2; ++mi)
#pragma unroll
    for (int ni = 0; ni < 4; ++ni) {
      const int col = n0 + wc * 64 + ni * 16 + (lane & 15);
      const float spp  = vecs[2 * 2048 + b * 256 + col];
      const float pstr = vecs[3 * 2048 + b * 256 + col];
      const float gst  = vecs[4 * 2048 + b * 256 + col];
#pragma unroll
      for (int r = 0; r < 4; ++r) {
        const int row = m0 + wr * 32 + mi * 16 + (lane >> 4) * 4 + r;
        const float pv = tanhf(acc[mi][ni][r] + spp);
        const float sp = bf2f(S[(size_t)row * 256 + col]);
        const float h = (sp + pstr * pv) * bf2f(G[(size_t)row * 256 + col]) * gst;
        H[(size_t)row * 256 + col] = f2bf(h);
        if ((row & 2047) == 2047) out[16777216 + b * 256 + col] = h;
      }
    }
}

// ---------------------------------------------------------------------------
// GEMM3: out[16384][1024] f32 = H @ wout^T. 64x256 tile, K=256 -> 8 k-steps.
// grid = 256 m x 4 n = 1024 blocks (4/CU). Wave = 32r x 128c (acc[2][8]).
__global__ __launch_bounds__(256) void gemm3_k(const short* __restrict__ H,
                                               const short* __restrict__ Wout,
                                               float* __restrict__ out) {
  __shared__ short As3[2][2048];   // [64][32]
  __shared__ short Bs3[2][8192];   // [256][32]
  const int tid = (int)threadIdx.x, lane = tid & 63, w = tid >> 6;
  const int wr = w >> 1, wc = w & 1;
  int bid = (int)blockIdx.x;
  bid = (bid & 7) * 128 + (bid >> 3);          // XCD swizzle (1024 % 8 == 0)
  const int m0 = (bid >> 2) * 64, n0 = (bid & 3) * 256;
  const short* gA = H + (size_t)m0 * 256;
  const short* gB = Wout + (size_t)n0 * 256;

  f32x4 acc[2][8];
#pragma unroll
  for (int mi = 0; mi < 2; ++mi)
#pragma unroll
    for (int ni = 0; ni < 8; ++ni)
#pragma unroll
      for (int r = 0; r < 4; ++r) acc[mi][ni][r] = 0.f;

#define STAGE3(buf, t)                                                        \
  {                                                                           \
    {                                                                         \
      const int g = tid;                                                      \
      gl16(gA + (size_t)(g >> 2) * 256 + (t) * 32 + (g & 3) * 8,              \
           As3[buf] + w * 512);                                               \
    }                                                                         \
    _Pragma("unroll")                                                         \
    for (int j = 0; j < 4; ++j) {                                             \
      const int g = j * 256 + tid;                                            \
      gl16(gB + (size_t)(g >> 2) * 256 + (t) * 32 + (g & 3) * 8,              \
           Bs3[buf] + (j * 256 + w * 64) * 8);                                \
    }                                                                         \
  }

  STAGE3(0, 0);
  __syncthreads();
  const int arow = lane & 15, ag = lane >> 4;
#pragma unroll 1
  for (int t = 0; t < 8; ++t) {
    if (t < 7) STAGE3((t + 1) & 1, t + 1);
    const short* Asb = As3[t & 1];
    const short* Bsb = Bs3[t & 1];
    bf16x8 af[2], bfv[8];
#pragma unroll
    for (int mi = 0; mi < 2; ++mi)
      af[mi] = *(const bf16x8*)(Asb + (wr * 32 + mi * 16 + arow) * 32 + ag * 8);
#pragma unroll
    for (int ni = 0; ni < 8; ++ni)
      bfv[ni] = *(const bf16x8*)(Bsb + (wc * 128 + ni * 16 + arow) * 32 + ag * 8);
#pragma unroll
    for (int mi = 0; mi < 2; ++mi)
#pragma unroll
      for (int ni = 0; ni < 8; ++ni)
        acc[mi][ni] = __builtin_amdgcn_mfma_f32_16x16x32_bf16(af[mi], bfv[ni], acc[mi][ni], 0, 0, 0);
    __syncthreads();
  }
#undef STAGE3

#pragma unroll
  for (int mi = 0; mi < 2; ++mi)
#pragma unroll
    for (int ni = 0; ni < 8; ++ni) {
      const int col = n0 + wc * 128 + ni * 16 + (lane & 15);
#pragma unroll
      for (int r = 0; r < 4; ++r) {
        const int row = m0 + wr * 32 + mi * 16 + (lane >> 4) * 4 + r;
        out[(size_t)row * 1024 + col] = acc[mi][ni][r];
      }
    }
}

// ---------------------------------------------------------------------------
extern "C" void kernel_launch(void* const* d_in, const int* in_sizes, int n_in,
                              void* d_out, int out_size, void* d_ws, size_t ws_size,
                              hipStream_t stream) {
  (void)in_sizes; (void)n_in; (void)out_size; (void)ws_size;
  const float* x      = (const float*)d_in[0];
  const float* prev   = (const float*)d_in[1];
  const float* W_in   = (const float*)d_in[2];
  const float* W_x    = (const float*)d_in[3];
  const float* W_s    = (const float*)d_in[4];
  const float* W_out  = (const float*)d_in[5];
  const float* W_gx   = (const float*)d_in[6];
  const float* b_gx   = (const float*)d_in[7];
  const float* W_gs   = (const float*)d_in[8];
  const float* b_gs   = (const float*)d_in[9];
  const float* W_dc   = (const float*)d_in[10];
  const float* b_dc   = (const float*)d_in[11];
  const float* W_pp   = (const float*)d_in[12];
  const float* b_pp   = (const float*)d_in[13];
  const float* W_pg   = (const float*)d_in[14];
  const float* b_pg   = (const float*)d_in[15];

  char* ws = (char*)d_ws;
  short* S    = (short*)(ws + OFF_S);
  short* G    = (short*)(ws + OFF_G);
  short* xbf  = (short*)(ws + OFF_XBF);
  short* H    = (short*)(ws + OFF_XBF);   // aliases xbf (dead after gemm1)
  short* wcat = (short*)(ws + OFF_WCAT);
  short* wpp  = (short*)(ws + OFF_WPP);
  short* wout = (short*)(ws + OFF_WOUT);
  float* vecs = (float*)(ws + OFF_VEC);
  float* out  = (float*)d_out;

  cvt_x_k<<<16384, 256, 0, stream>>>(x, xbf);
  prep_ws_k<<<4512, 256, 0, stream>>>(W_in, W_x, W_gx, W_dc, W_pp, W_out,
                                      wcat, wpp, wout, prev, W_s, b_dc, b_pp,
                                      W_pg, b_pg, W_gs, b_gs, vecs);
  gemm1sg_k<<<512, 512, 0, stream>>>(xbf, wcat, prev, b_gx, vecs, S, G);
  gemm2h_k<<<512, 256, 0, stream>>>(S, G, wpp, vecs, H, out);
  gemm3_k<<<1024, 256, 0, stream>>>(H, wout, out);
}

// Round 21
// 103.179 us; speedup vs baseline: 1.0233x; 1.0233x over previous
//
#include <hip/hip_runtime.h>
#include <hip/hip_bf16.h>
#include <math.h>

// ---------------------------------------------------------------------------
// GatedTinyMambaLayer: B=8, T=2048, DM=1024, DS=256
// Pipeline: prep_all (grid-stride cvt_x + weight prep + state GEMVs, merged)
// -> gemm1sg (128x192, BK=64, 1 barrier/K-tile, fused S,G) -> gemm2h -> gemm3.
// wcat: 4 groups of 192 rows: {W_in+W_x[g*64..], W_gx[g*64..], W_dc[g*64..]}.
// R21: cvt_x rewritten per G11 (grid <= 2048 blocks, grid-stride, 8 float4
// iters/thread unrolled -> 8 loads in flight/thread). All prior one-shot
// forms (R3/R5/R19/R20) sat at ~2.5TB/s; m13's 6.3TB/s copy used this form.
// ---------------------------------------------------------------------------

typedef __attribute__((ext_vector_type(4)))  float f32x4;
typedef __attribute__((ext_vector_type(8)))  short bf16x8;

#define DEV static __device__ __forceinline__

DEV float bf2f(short u) {
  union { float f; unsigned i; } v; v.i = ((unsigned)(unsigned short)u) << 16; return v.f;
}
DEV short f2bf(float f) {  // round-to-nearest-even
  union { float f; unsigned i; } v; v.f = f;
  unsigned x = v.i;
  return (short)((x + 0x7fffu + ((x >> 16) & 1u)) >> 16);
}
DEV float sigmoidf_(float x) { return 1.f / (1.f + expf(-x)); }

DEV void gl16(const void* g, void* l) {
  __builtin_amdgcn_global_load_lds(
      (const __attribute__((address_space(1))) void*)(g),
      (__attribute__((address_space(3))) void*)(l), 16, 0, 0);
}

// ---- workspace layout (bytes) ---------------------------------------------
static const size_t OFF_S    = 0;                   // bf16 [16384][256]
static const size_t OFF_G    = 8388608;             // bf16 [16384][256]
static const size_t OFF_XBF  = 25165824;            // bf16 [16384][1024]; H aliases (dead after gemm1)
static const size_t OFF_WCAT = OFF_XBF + 33554432;  // bf16 [768][1024] (192-row groups)
static const size_t OFF_WPP  = OFF_WCAT + 1572864;  // bf16 [256][256]  (W_pp[:, :256])
static const size_t OFF_WOUT = OFF_WPP + 131072;    // bf16 [1024][256]
static const size_t OFF_VEC  = OFF_WOUT + 524288;   // f32 [5][2048]: sdc,sws,spp,pstr,gst

// ---------------------------------------------------------------------------
// prep_all: [0,2048) grid-stride cvt_x ; [2048,6400) weight prep ;
//           [6400,6560) state GEMVs
__global__ __launch_bounds__(256, 1) void prep_all_k(
    const float* __restrict__ x, short* __restrict__ xbf,
    const float* __restrict__ W_in, const float* __restrict__ W_x,
    const float* __restrict__ W_gx, const float* __restrict__ W_dc,
    const float* __restrict__ W_pp, const float* __restrict__ W_out,
    short* __restrict__ wcat, short* __restrict__ wpp, short* __restrict__ wout,
    const float* __restrict__ prev, const float* __restrict__ Ws,
    const float* __restrict__ bdc, const float* __restrict__ bpp,
    const float* __restrict__ Wpg, const float* __restrict__ bpg,
    const float* __restrict__ Wgs, const float* __restrict__ bgs,
    float* __restrict__ vecs) {
  const int bid = (int)blockIdx.x, tid = (int)threadIdx.x;
  if (bid < 2048) {  // ---- cvt_x: grid-stride, 8 float4 iters, loads first
    const size_t u0 = (size_t)bid * 256 + tid;   // float4-unit index base
    float4 v[8];
#pragma unroll
    for (int it = 0; it < 8; ++it)
      v[it] = *(const float4*)(x + (u0 + (size_t)it * 524288) * 4);
#pragma unroll
    for (int it = 0; it < 8; ++it) {
      short4 o;
      o.x = f2bf(v[it].x); o.y = f2bf(v[it].y);
      o.z = f2bf(v[it].z); o.w = f2bf(v[it].w);
      *(short4*)(xbf + (u0 + (size_t)it * 524288) * 4) = o;
    }
  } else if (bid < 6400) {  // ---- weight prep (192-row groups)
    const int idx = (bid - 2048) * 256 + tid;
    const int N_WCAT = 768 * 1024, N_WPP = 256 * 256;
    if (idx < N_WCAT) {
      const int r = idx >> 10, k = idx & 1023;
      const int g = r / 192, j = r % 192;
      float v;
      if (j < 64)       v = W_in[(g * 64 + j) * 1024 + k] + W_x[(g * 64 + j) * 1024 + k];
      else if (j < 128) v = W_gx[(g * 64 + j - 64) * 1024 + k];
      else              v = W_dc[(g * 64 + j - 128) * 1280 + k];
      wcat[idx] = f2bf(v);
    } else if (idx < N_WCAT + N_WPP) {
      const int j = idx - N_WCAT, o = j >> 8, k = j & 255;
      wpp[j] = f2bf(W_pp[o * 512 + k]);          // W_pp[:, :256]
    } else {
      const int j = idx - N_WCAT - N_WPP, o = j >> 8, k = j & 255;
      wout[j] = f2bf(W_out[o * 256 + k]);
    }
  } else {  // ---- per-batch state GEMVs (coalesced, butterfly reduce)
    const int sb = bid - 6400;
    const int b = sb / 20, rem = sb % 20, m = rem >> 2, oq = rem & 3;
    const int lane = tid & 63, w = tid >> 6;
    const float4 sv = *(const float4*)(prev + b * 256 + lane * 4);
    const float* Wb; const float* bias; int stride, off;
    if (m == 0)      { Wb = W_dc; stride = 1280; off = 1024; bias = bdc; }
    else if (m == 1) { Wb = Ws;   stride = 256;  off = 0;    bias = nullptr; }
    else if (m == 2) { Wb = W_pp; stride = 512;  off = 256;  bias = bpp; }
    else if (m == 3) { Wb = Wpg;  stride = 256;  off = 0;    bias = bpg; }
    else             { Wb = Wgs;  stride = 256;  off = 0;    bias = bgs; }
    const int o0 = oq * 64 + w * 16;
#pragma unroll 4
    for (int i = 0; i < 16; ++i) {
      const int o = o0 + i;
      const float4 wv = *(const float4*)(Wb + (size_t)o * stride + off + lane * 4);
      float p = wv.x * sv.x + wv.y * sv.y + wv.z * sv.z + wv.w * sv.w;
#pragma unroll
      for (int d = 32; d >= 1; d >>= 1) p += __shfl_xor(p, d, 64);
      if (lane == 0) {
        float r = (m == 1) ? 0.5f * p : p + bias[o];
        if (m >= 3) r = sigmoidf_(r);
        vecs[m * 2048 + b * 256 + o] = r;
      }
    }
  }
}

// ---------------------------------------------------------------------------
// GEMM1+SG BK=64: 128x192 tile, 512 threads (8 waves, each 16 rows x 192
// cols, acc[12]). grid = 128 m x 4 grp = 512 blocks (2/CU, 80KB LDS).
// Per K-tile: {stage(t+1) -> A-frag reads -> 3 component phases x 8 MFMA ->
// vmcnt(0) [own stages, issued a tile ago] -> s_barrier}. One barrier/tile.
// Epilogue: S = prev*exp(-.05*sig(dc+sdc)) + ix + sws ; G = sig(gx+bgx).
__global__ __launch_bounds__(512) void gemm1sg_k(const short* __restrict__ A,
                                                 const short* __restrict__ Bm,
                                                 const float* __restrict__ prev,
                                                 const float* __restrict__ bgx,
                                                 const float* __restrict__ vecs,
                                                 short* __restrict__ S,
                                                 short* __restrict__ G) {
  __shared__ short As[2][8192];    // [128][64] dbuf, granule-XOR swizzled
  __shared__ short Bs[2][12288];   // [192][64] dbuf
  const int tid = (int)threadIdx.x, lane = tid & 63, w = tid >> 6;
  int bid = (int)blockIdx.x;
  bid = (bid & 7) * 64 + (bid >> 3);           // XCD swizzle (512 % 8 == 0)
  const int mt = bid >> 2, grp = bid & 3;
  const int m0 = mt * 128, b = m0 >> 11;       // one batch per 128-row tile
  const short* gA = A + (size_t)m0 * 1024;
  const short* gB = Bm + (size_t)(grp * 192) * 1024;

  f32x4 acc[12];
#pragma unroll
  for (int ni = 0; ni < 12; ++ni)
#pragma unroll
    for (int r = 0; r < 4; ++r) acc[ni][r] = 0.f;

#define STGA(buf, t)                                                          \
  {                                                                           \
    _Pragma("unroll")                                                         \
    for (int j = 0; j < 2; ++j) {                                             \
      const int Gr = j * 512 + tid, r = Gr >> 3, g = Gr & 7;                  \
      gl16(gA + (size_t)r * 1024 + (t) * 64 + ((g ^ (r & 7)) * 8),            \
           As[buf] + Gr * 8);                                                 \
    }                                                                         \
  }
#define STGB(buf, t)                                                          \
  {                                                                           \
    _Pragma("unroll")                                                         \
    for (int j = 0; j < 3; ++j) {                                             \
      const int Gr = j * 512 + tid, r = Gr >> 3, g = Gr & 7;                  \
      gl16(gB + (size_t)r * 1024 + (t) * 64 + ((g ^ (r & 7)) * 8),            \
           Bs[buf] + Gr * 8);                                                 \
    }                                                                         \
  }

  STGA(0, 0); STGB(0, 0);
  asm volatile("s_waitcnt vmcnt(0)" ::: "memory");
  __builtin_amdgcn_s_barrier();

  const int arow = lane & 15, ag = lane >> 4;
  const int rowA = w * 16 + arow;
  const int swzA = rowA & 7;
#pragma unroll 1
  for (int t = 0; t < 16; ++t) {
    const short* sA = As[t & 1];
    const short* sB = Bs[t & 1];
    if (t < 15) { STGA((t + 1) & 1, t + 1); STGB((t + 1) & 1, t + 1); }
    bf16x8 af[2];
#pragma unroll
    for (int ks = 0; ks < 2; ++ks)
      af[ks] = *(const bf16x8*)(sA + rowA * 64 + (((ks * 4 + ag) ^ swzA) << 3));
    __builtin_amdgcn_s_setprio(1);
#pragma unroll
    for (int q = 0; q < 3; ++q) {
#pragma unroll
      for (int fj = 0; fj < 4; ++fj) {
        const int r = q * 64 + fj * 16 + arow;
#pragma unroll
        for (int ks = 0; ks < 2; ++ks) {
          const bf16x8 bf = *(const bf16x8*)(sB + r * 64 + (((ks * 4 + ag) ^ (r & 7)) << 3));
          acc[q * 4 + fj] = __builtin_amdgcn_mfma_f32_16x16x32_bf16(
              af[ks], bf, acc[q * 4 + fj], 0, 0, 0);
        }
      }
    }
    __builtin_amdgcn_s_setprio(0);
    if (t < 15) { asm volatile("s_waitcnt vmcnt(0)" ::: "memory"); }
    __builtin_amdgcn_s_barrier();
  }
#undef STGA
#undef STGB

  // epilogue: acc[0-3] = ix, [4-7] = gx, [8-11] = dc for cols grp*64..+63
  const int quad = lane >> 4;
#pragma unroll
  for (int cidx = 0; cidx < 4; ++cidx) {
    const int cg = grp * 64 + cidx * 16 + arow;
    const float sdc = vecs[0 * 2048 + b * 256 + cg];
    const float sws = vecs[1 * 2048 + b * 256 + cg];
    const float pv  = prev[b * 256 + cg];
    const float bg  = bgx[cg];
#pragma unroll
    for (int r = 0; r < 4; ++r) {
      const int row = m0 + w * 16 + quad * 4 + r;
      const float dec = expf(-0.05f * sigmoidf_(acc[8 + cidx][r] + sdc));
      const float sp = pv * dec + acc[cidx][r] + sws;
      const float g = sigmoidf_(acc[4 + cidx][r] + bg);
      S[(size_t)row * 256 + cg] = f2bf(sp);
      G[(size_t)row * 256 + cg] = f2bf(g);
    }
  }
}

// ---------------------------------------------------------------------------
// GEMM2 + elementwise: P = S @ wpp^T; h = (S + pstr*tanh(P+spp)) * G * gst
// 64x128 tile, grid = 256 m x 2 n = 512 blocks (2/CU). Wave = 32r x 64c.
__global__ __launch_bounds__(256) void gemm2h_k(const short* __restrict__ S,
                                                const short* __restrict__ G,
                                                const short* __restrict__ Wpp,
                                                const float* __restrict__ vecs,
                                                short* __restrict__ H,
                                                float* __restrict__ out) {
  __shared__ short As2[2][2048];   // [64][32]
  __shared__ short Bs2[2][4096];   // [128][32]
  const int tid = (int)threadIdx.x, lane = tid & 63, w = tid >> 6;
  const int wr = w >> 1, wc = w & 1;
  int bid = (int)blockIdx.x;
  bid = (bid & 7) * 64 + (bid >> 3);           // XCD swizzle (512 % 8 == 0)
  const int m0 = (bid >> 1) * 64, n0 = (bid & 1) * 128;
  const int b = m0 >> 11;
  const short* gA = S + (size_t)m0 * 256;
  const short* gB = Wpp + (size_t)n0 * 256;

  f32x4 acc[2][4];
#pragma unroll
  for (int mi = 0; mi < 2; ++mi)
#pragma unroll
    for (int ni = 0; ni < 4; ++ni)
#pragma unroll
      for (int r = 0; r < 4; ++r) acc[mi][ni][r] = 0.f;

#define STAGE2(buf, t)                                                        \
  {                                                                           \
    {                                                                         \
      const int g = tid;                                                      \
      gl16(gA + (size_t)(g >> 2) * 256 + (t) * 32 + (g & 3) * 8,              \
           As2[buf] + w * 512);                                               \
    }                                                                         \
    _Pragma("unroll")                                                         \
    for (int j = 0; j < 2; ++j) {                                             \
      const int g = j * 256 + tid;                                            \
      gl16(gB + (size_t)(g >> 2) * 256 + (t) * 32 + (g & 3) * 8,              \
           Bs2[buf] + (j * 256 + w * 64) * 8);                                \
    }                                                                         \
  }

  STAGE2(0, 0);
  __syncthreads();
  const int arow = lane & 15, ag = lane >> 4;
#pragma unroll 1
  for (int t = 0; t < 8; ++t) {
    if (t < 7) STAGE2((t + 1) & 1, t + 1);
    const short* Asb = As2[t & 1];
    const short* Bsb = Bs2[t & 1];
    bf16x8 af[2], bfv[4];
#pragma unroll
    for (int mi = 0; mi < 2; ++mi)
      af[mi] = *(const bf16x8*)(Asb + (wr * 32 + mi * 16 + arow) * 32 + ag * 8);
#pragma unroll
    for (int ni = 0; ni < 4; ++ni)
      bfv[ni] = *(const bf16x8*)(Bsb + (wc * 64 + ni * 16 + arow) * 32 + ag * 8);
#pragma unroll
    for (int mi = 0; mi < 2; ++mi)
#pragma unroll
      for (int ni = 0; ni < 4; ++ni)
        acc[mi][ni] = __builtin_amdgcn_mfma_f32_16x16x32_bf16(af[mi], bfv[ni], acc[mi][ni], 0, 0, 0);
    __syncthreads();
  }
#undef STAGE2

#pragma unroll
  for (int mi = 0; mi < 2; ++mi)
#pragma unroll
    for (int ni = 0; ni < 4; ++ni) {
      const int col = n0 + wc * 64 + ni * 16 + (lane & 15);
      const float spp  = vecs[2 * 2048 + b * 256 + col];
      const float pstr = vecs[3 * 2048 + b * 256 + col];
      const float gst  = vecs[4 * 2048 + b * 256 + col];
#pragma unroll
      for (int r = 0; r < 4; ++r) {
        const int row = m0 + wr * 32 + mi * 16 + (lane >> 4) * 4 + r;
        const float pv = tanhf(acc[mi][ni][r] + spp);
        const float sp = bf2f(S[(size_t)row * 256 + col]);
        const float h = (sp + pstr * pv) * bf2f(G[(size_t)row * 256 + col]) * gst;
        H[(size_t)row * 256 + col] = f2bf(h);
        if ((row & 2047) == 2047) out[16777216 + b * 256 + col] = h;
      }
    }
}

// ---------------------------------------------------------------------------
// GEMM3: out[16384][1024] f32 = H @ wout^T. 64x256 tile, K=256 -> 8 k-steps.
// grid = 256 m x 4 n = 1024 blocks (4/CU). Wave = 32r x 128c (acc[2][8]).
__global__ __launch_bounds__(256) void gemm3_k(const short* __restrict__ H,
                                               const short* __restrict__ Wout,
                                               float* __restrict__ out) {
  __shared__ short As3[2][2048];   // [64][32]
  __shared__ short Bs3[2][8192];   // [256][32]
  const int tid = (int)threadIdx.x, lane = tid & 63, w = tid >> 6;
  const int wr = w >> 1, wc = w & 1;
  int bid = (int)blockIdx.x;
  bid = (bid & 7) * 128 + (bid >> 3);          // XCD swizzle (1024 % 8 == 0)
  const int m0 = (bid >> 2) * 64, n0 = (bid & 3) * 256;
  const short* gA = H + (size_t)m0 * 256;
  const short* gB = Wout + (size_t)n0 * 256;

  f32x4 acc[2][8];
#pragma unroll
  for (int mi = 0; mi < 2; ++mi)
#pragma unroll
    for (int ni = 0; ni < 8; ++ni)
#pragma unroll
      for (int r = 0; r < 4; ++r) acc[mi][ni][r] = 0.f;

#define STAGE3(buf, t)                                                        \
  {                                                                           \
    {                                                                         \
      const int g = tid;                                                      \
      gl16(gA + (size_t)(g >> 2) * 256 + (t) * 32 + (g & 3) * 8,              \
           As3[buf] + w * 512);                                               \
    }                                                                         \
    _Pragma("unroll")                                                         \
    for (int j = 0; j < 4; ++j) {                                             \
      const int g = j * 256 + tid;                                            \
      gl16(gB + (size_t)(g >> 2) * 256 + (t) * 32 + (g & 3) * 8,              \
           Bs3[buf] + (j * 256 + w * 64) * 8);                                \
    }                                                                         \
  }

  STAGE3(0, 0);
  __syncthreads();
  const int arow = lane & 15, ag = lane >> 4;
#pragma unroll 1
  for (int t = 0; t < 8; ++t) {
    if (t < 7) STAGE3((t + 1) & 1, t + 1);
    const short* Asb = As3[t & 1];
    const short* Bsb = Bs3[t & 1];
    bf16x8 af[2], bfv[8];
#pragma unroll
    for (int mi = 0; mi < 2; ++mi)
      af[mi] = *(const bf16x8*)(Asb + (wr * 32 + mi * 16 + arow) * 32 + ag * 8);
#pragma unroll
    for (int ni = 0; ni < 8; ++ni)
      bfv[ni] = *(const bf16x8*)(Bsb + (wc * 128 + ni * 16 + arow) * 32 + ag * 8);
#pragma unroll
    for (int mi = 0; mi < 2; ++mi)
#pragma unroll
      for (int ni = 0; ni < 8; ++ni)
        acc[mi][ni] = __builtin_amdgcn_mfma_f32_16x16x32_bf16(af[mi], bfv[ni], acc[mi][ni], 0, 0, 0);
    __syncthreads();
  }
#undef STAGE3

#pragma unroll
  for (int mi = 0; mi < 2; ++mi)
#pragma unroll
    for (int ni = 0; ni < 8; ++ni) {
      const int col = n0 + wc * 128 + ni * 16 + (lane & 15);
#pragma unroll
      for (int r = 0; r < 4; ++r) {
        const int row = m0 + wr * 32 + mi * 16 + (lane >> 4) * 4 + r;
        out[(size_t)row * 1024 + col] = acc[mi][ni][r];
      }
    }
}

// ---------------------------------------------------------------------------
extern "C" void kernel_launch(void* const* d_in, const int* in_sizes, int n_in,
                              void* d_out, int out_size, void* d_ws, size_t ws_size,
                              hipStream_t stream) {
  (void)in_sizes; (void)n_in; (void)out_size; (void)ws_size;
  const float* x      = (const float*)d_in[0];
  const float* prev   = (const float*)d_in[1];
  const float* W_in   = (const float*)d_in[2];
  const float* W_x    = (const float*)d_in[3];
  const float* W_s    = (const float*)d_in[4];
  const float* W_out  = (const float*)d_in[5];
  const float* W_gx   = (const float*)d_in[6];
  const float* b_gx   = (const float*)d_in[7];
  const float* W_gs   = (const float*)d_in[8];
  const float* b_gs   = (const float*)d_in[9];
  const float* W_dc   = (const float*)d_in[10];
  const float* b_dc   = (const float*)d_in[11];
  const float* W_pp   = (const float*)d_in[12];
  const float* b_pp   = (const float*)d_in[13];
  const float* W_pg   = (const float*)d_in[14];
  const float* b_pg   = (const float*)d_in[15];

  char* ws = (char*)d_ws;
  short* S    = (short*)(ws + OFF_S);
  short* G    = (short*)(ws + OFF_G);
  short* xbf  = (short*)(ws + OFF_XBF);
  short* H    = (short*)(ws + OFF_XBF);   // aliases xbf (dead after gemm1)
  short* wcat = (short*)(ws + OFF_WCAT);
  short* wpp  = (short*)(ws + OFF_WPP);
  short* wout = (short*)(ws + OFF_WOUT);
  float* vecs = (float*)(ws + OFF_VEC);
  float* out  = (float*)d_out;

  prep_all_k<<<6560, 256, 0, stream>>>(x, xbf, W_in, W_x, W_gx, W_dc, W_pp, W_out,
                                       wcat, wpp, wout, prev, W_s, b_dc, b_pp,
                                       W_pg, b_pg, W_gs, b_gs, vecs);
  gemm1sg_k<<<512, 512, 0, stream>>>(xbf, wcat, prev, b_gx, vecs, S, G);
  gemm2h_k<<<512, 256, 0, stream>>>(S, G, wpp, vecs, H, out);
  gemm3_k<<<1024, 256, 0, stream>>>(H, wout, out);
}

// Round 22
// 97.337 us; speedup vs baseline: 1.0847x; 1.0600x over previous
//
#include <hip/hip_runtime.h>
#include <hip/hip_bf16.h>
#include <math.h>

// ---------------------------------------------------------------------------
// GatedTinyMambaLayer: B=8, T=2048, DM=1024, DS=256
// Pipeline: prep_ws (weight prep + state GEMVs; NO cvt_x pass) ->
// gemm1sg (128x192, BK=64, 1 barrier/K-tile, A = x f32 reg-staged with
// T14 async split: loads issued at tile start, cvt+ds_write after MFMAs;
// B via global_load_lds; fused S,G epilogue) -> gemm2h -> gemm3.
// wcat: 4 groups of 192 rows: {W_in+W_x[g*64..], W_gx[g*64..], W_dc[g*64..]}.
// R22 journal: 5 cvt_x forms all ~2.4TB/s (~38-43us) -> pass deleted;
// conversion folded into gemm1sg staging (R4's mechanism, R18's skeleton:
// loads get a full tile of MFMA to land; ds_write drained by the per-tile
// lgkmcnt(0)+vmcnt(0)+barrier that already exists).
// ---------------------------------------------------------------------------

typedef __attribute__((ext_vector_type(4)))  float f32x4;
typedef __attribute__((ext_vector_type(8)))  short bf16x8;

#define DEV static __device__ __forceinline__

DEV float bf2f(short u) {
  union { float f; unsigned i; } v; v.i = ((unsigned)(unsigned short)u) << 16; return v.f;
}
DEV short f2bf(float f) {  // round-to-nearest-even
  union { float f; unsigned i; } v; v.f = f;
  unsigned x = v.i;
  return (short)((x + 0x7fffu + ((x >> 16) & 1u)) >> 16);
}
DEV unsigned pk_bf16(float lo, float hi) {  // -> v_cvt_pk_bf16_f32
  __hip_bfloat162 h = __float22bfloat162_rn(make_float2(lo, hi));
  return *(unsigned*)&h;
}
DEV float sigmoidf_(float x) { return 1.f / (1.f + expf(-x)); }

DEV void gl16(const void* g, void* l) {
  __builtin_amdgcn_global_load_lds(
      (const __attribute__((address_space(1))) void*)(g),
      (__attribute__((address_space(3))) void*)(l), 16, 0, 0);
}

// ---- workspace layout (bytes) ---------------------------------------------
static const size_t OFF_S    = 0;                   // bf16 [16384][256]
static const size_t OFF_G    = 8388608;             // bf16 [16384][256]
static const size_t OFF_H    = 16777216;            // bf16 [16384][256]
static const size_t OFF_WCAT = 25165824;            // bf16 [768][1024] (192-row groups)
static const size_t OFF_WPP  = OFF_WCAT + 1572864;  // bf16 [256][256]  (W_pp[:, :256])
static const size_t OFF_WOUT = OFF_WPP + 131072;    // bf16 [1024][256]
static const size_t OFF_VEC  = OFF_WOUT + 524288;   // f32 [5][2048]: sdc,sws,spp,pstr,gst

// ---------------------------------------------------------------------------
// prep_ws: blocks [0,4352) weight prep ; [4352,4512) state GEMVs
__global__ __launch_bounds__(256, 1) void prep_ws_k(
    const float* __restrict__ W_in, const float* __restrict__ W_x,
    const float* __restrict__ W_gx, const float* __restrict__ W_dc,
    const float* __restrict__ W_pp, const float* __restrict__ W_out,
    short* __restrict__ wcat, short* __restrict__ wpp, short* __restrict__ wout,
    const float* __restrict__ prev, const float* __restrict__ Ws,
    const float* __restrict__ bdc, const float* __restrict__ bpp,
    const float* __restrict__ Wpg, const float* __restrict__ bpg,
    const float* __restrict__ Wgs, const float* __restrict__ bgs,
    float* __restrict__ vecs) {
  const int bid = (int)blockIdx.x, tid = (int)threadIdx.x;
  if (bid < 4352) {  // ---- weight prep (192-row groups)
    const int idx = bid * 256 + tid;
    const int N_WCAT = 768 * 1024, N_WPP = 256 * 256;
    if (idx < N_WCAT) {
      const int r = idx >> 10, k = idx & 1023;
      const int g = r / 192, j = r % 192;
      float v;
      if (j < 64)       v = W_in[(g * 64 + j) * 1024 + k] + W_x[(g * 64 + j) * 1024 + k];
      else if (j < 128) v = W_gx[(g * 64 + j - 64) * 1024 + k];
      else              v = W_dc[(g * 64 + j - 128) * 1280 + k];
      wcat[idx] = f2bf(v);
    } else if (idx < N_WCAT + N_WPP) {
      const int j = idx - N_WCAT, o = j >> 8, k = j & 255;
      wpp[j] = f2bf(W_pp[o * 512 + k]);          // W_pp[:, :256]
    } else {
      const int j = idx - N_WCAT - N_WPP, o = j >> 8, k = j & 255;
      wout[j] = f2bf(W_out[o * 256 + k]);
    }
  } else {  // ---- per-batch state GEMVs (coalesced, butterfly reduce)
    const int sb = bid - 4352;
    const int b = sb / 20, rem = sb % 20, m = rem >> 2, oq = rem & 3;
    const int lane = tid & 63, w = tid >> 6;
    const float4 sv = *(const float4*)(prev + b * 256 + lane * 4);
    const float* Wb; const float* bias; int stride, off;
    if (m == 0)      { Wb = W_dc; stride = 1280; off = 1024; bias = bdc; }
    else if (m == 1) { Wb = Ws;   stride = 256;  off = 0;    bias = nullptr; }
    else if (m == 2) { Wb = W_pp; stride = 512;  off = 256;  bias = bpp; }
    else if (m == 3) { Wb = Wpg;  stride = 256;  off = 0;    bias = bpg; }
    else             { Wb = Wgs;  stride = 256;  off = 0;    bias = bgs; }
    const int o0 = oq * 64 + w * 16;
#pragma unroll 4
    for (int i = 0; i < 16; ++i) {
      const int o = o0 + i;
      const float4 wv = *(const float4*)(Wb + (size_t)o * stride + off + lane * 4);
      float p = wv.x * sv.x + wv.y * sv.y + wv.z * sv.z + wv.w * sv.w;
#pragma unroll
      for (int d = 32; d >= 1; d >>= 1) p += __shfl_xor(p, d, 64);
      if (lane == 0) {
        float r = (m == 1) ? 0.5f * p : p + bias[o];
        if (m >= 3) r = sigmoidf_(r);
        vecs[m * 2048 + b * 256 + o] = r;
      }
    }
  }
}

// ---------------------------------------------------------------------------
// GEMM1+SG BK=64: 128x192 tile, 512 threads (8 waves, each 16 rows x 192
// cols, acc[12]). grid = 128 m x 4 grp = 512 blocks (2/CU, 80KB LDS).
// A (x, f32): T14 async reg-staging — f32 loads for tile t+1 issued at tile-t
// START, cvt_pk + ds_write AFTER the MFMA cluster (loads have a whole tile to
// land); drained by lgkmcnt(0)+vmcnt(0)+s_barrier (already per-tile).
// B (wcat, bf16): global_load_lds, granule-XOR-swizzled source.
// Epilogue: S = prev*exp(-.05*sig(dc+sdc)) + ix + sws ; G = sig(gx+bgx).
__global__ __launch_bounds__(512) void gemm1sg_k(const float* __restrict__ X,
                                                 const short* __restrict__ Bm,
                                                 const float* __restrict__ prev,
                                                 const float* __restrict__ bgx,
                                                 const float* __restrict__ vecs,
                                                 short* __restrict__ S,
                                                 short* __restrict__ G) {
  __shared__ short As[2][8192];    // [128][64] bf16 dbuf, granule-XOR swizzled
  __shared__ short Bs[2][12288];   // [192][64] bf16 dbuf
  const int tid = (int)threadIdx.x, lane = tid & 63, w = tid >> 6;
  int bid = (int)blockIdx.x;
  bid = (bid & 7) * 64 + (bid >> 3);           // XCD swizzle (512 % 8 == 0)
  const int mt = bid >> 2, grp = bid & 3;
  const int m0 = mt * 128, b = m0 >> 11;       // one batch per 128-row tile
  const short* gB = Bm + (size_t)(grp * 192) * 1024;

  // A reg-stage addressing: granule Gr = j*512+tid -> row r=Gr>>3, g=Gr&7;
  // source f32 x[(m0+r)*1024 + t*64 + (g^(r&7))*8 .. +8]
  const int GrA[2] = {tid, 512 + tid};
  const int rA0 = GrA[0] >> 3, gA0 = (GrA[0] & 7) ^ (rA0 & 7);
  const int rA1 = GrA[1] >> 3, gA1 = (GrA[1] & 7) ^ (rA1 & 7);
  const float* xr0 = X + (size_t)(m0 + rA0) * 1024 + gA0 * 8;
  const float* xr1 = X + (size_t)(m0 + rA1) * 1024 + gA1 * 8;

  f32x4 acc[12];
#pragma unroll
  for (int ni = 0; ni < 12; ++ni)
#pragma unroll
    for (int r = 0; r < 4; ++r) acc[ni][r] = 0.f;

#define LOADA(va, t)                                                          \
  {                                                                           \
    va[0][0] = *(const float4*)(xr0 + (t) * 64);                              \
    va[0][1] = *(const float4*)(xr0 + (t) * 64 + 4);                          \
    va[1][0] = *(const float4*)(xr1 + (t) * 64);                              \
    va[1][1] = *(const float4*)(xr1 + (t) * 64 + 4);                          \
  }
#define WRITEA(va, buf)                                                       \
  {                                                                           \
    _Pragma("unroll")                                                         \
    for (int j = 0; j < 2; ++j) {                                             \
      uint4 pk;                                                               \
      pk.x = pk_bf16(va[j][0].x, va[j][0].y);                                 \
      pk.y = pk_bf16(va[j][0].z, va[j][0].w);                                 \
      pk.z = pk_bf16(va[j][1].x, va[j][1].y);                                 \
      pk.w = pk_bf16(va[j][1].z, va[j][1].w);                                 \
      *(uint4*)(As[buf] + GrA[j] * 8) = pk;                                   \
    }                                                                         \
  }
#define STGB(buf, t)                                                          \
  {                                                                           \
    _Pragma("unroll")                                                         \
    for (int j = 0; j < 3; ++j) {                                             \
      const int Gr = j * 512 + tid, r = Gr >> 3, g = Gr & 7;                  \
      gl16(gB + (size_t)r * 1024 + (t) * 64 + ((g ^ (r & 7)) * 8),            \
           Bs[buf] + Gr * 8);                                                 \
    }                                                                         \
  }

  // prologue: A(0) reg->cvt->LDS ; B(0) gload_lds
  {
    float4 va[2][2];
    LOADA(va, 0);
    STGB(0, 0);
    WRITEA(va, 0);
  }
  asm volatile("s_waitcnt vmcnt(0) lgkmcnt(0)" ::: "memory");
  __builtin_amdgcn_s_barrier();

  const int arow = lane & 15, ag = lane >> 4;
  const int rowA = w * 16 + arow;
  const int swzA = rowA & 7;
#pragma unroll 1
  for (int t = 0; t < 16; ++t) {
    const short* sA = As[t & 1];
    const short* sB = Bs[t & 1];
    float4 va[2][2];
    if (t < 15) { LOADA(va, t + 1); STGB((t + 1) & 1, t + 1); }
    bf16x8 af[2];
#pragma unroll
    for (int ks = 0; ks < 2; ++ks)
      af[ks] = *(const bf16x8*)(sA + rowA * 64 + (((ks * 4 + ag) ^ swzA) << 3));
    __builtin_amdgcn_s_setprio(1);
#pragma unroll
    for (int q = 0; q < 3; ++q) {
#pragma unroll
      for (int fj = 0; fj < 4; ++fj) {
        const int r = q * 64 + fj * 16 + arow;
#pragma unroll
        for (int ks = 0; ks < 2; ++ks) {
          const bf16x8 bf = *(const bf16x8*)(sB + r * 64 + (((ks * 4 + ag) ^ (r & 7)) << 3));
          acc[q * 4 + fj] = __builtin_amdgcn_mfma_f32_16x16x32_bf16(
              af[ks], bf, acc[q * 4 + fj], 0, 0, 0);
        }
      }
    }
    __builtin_amdgcn_s_setprio(0);
    if (t < 15) {
      WRITEA(va, (t + 1) & 1);   // compiler waits va's vmcnt (landed under MFMAs)
      asm volatile("s_waitcnt vmcnt(0) lgkmcnt(0)" ::: "memory");
    }
    __builtin_amdgcn_s_barrier();
  }
#undef LOADA
#undef WRITEA
#undef STGB

  // epilogue: acc[0-3] = ix, [4-7] = gx, [8-11] = dc for cols grp*64..+63
  const int quad = lane >> 4;
#pragma unroll
  for (int cidx = 0; cidx < 4; ++cidx) {
    const int cg = grp * 64 + cidx * 16 + arow;
    const float sdc = vecs[0 * 2048 + b * 256 + cg];
    const float sws = vecs[1 * 2048 + b * 256 + cg];
    const float pv  = prev[b * 256 + cg];
    const float bg  = bgx[cg];
#pragma unroll
    for (int r = 0; r < 4; ++r) {
      const int row = m0 + w * 16 + quad * 4 + r;
      const float dec = expf(-0.05f * sigmoidf_(acc[8 + cidx][r] + sdc));
      const float sp = pv * dec + acc[cidx][r] + sws;
      const float g = sigmoidf_(acc[4 + cidx][r] + bg);
      S[(size_t)row * 256 + cg] = f2bf(sp);
      G[(size_t)row * 256 + cg] = f2bf(g);
    }
  }
}

// ---------------------------------------------------------------------------
// GEMM2 + elementwise: P = S @ wpp^T; h = (S + pstr*tanh(P+spp)) * G * gst
// 64x128 tile, grid = 256 m x 2 n = 512 blocks (2/CU). Wave = 32r x 64c.
__global__ __launch_bounds__(256) void gemm2h_k(const short* __restrict__ S,
                                                const short* __restrict__ G,
                                                const short* __restrict__ Wpp,
                                                const float* __restrict__ vecs,
                                                short* __restrict__ H,
                                                float* __restrict__ out) {
  __shared__ short As2[2][2048];   // [64][32]
  __shared__ short Bs2[2][4096];   // [128][32]
  const int tid = (int)threadIdx.x, lane = tid & 63, w = tid >> 6;
  const int wr = w >> 1, wc = w & 1;
  int bid = (int)blockIdx.x;
  bid = (bid & 7) * 64 + (bid >> 3);           // XCD swizzle (512 % 8 == 0)
  const int m0 = (bid >> 1) * 64, n0 = (bid & 1) * 128;
  const int b = m0 >> 11;
  const short* gA = S + (size_t)m0 * 256;
  const short* gB = Wpp + (size_t)n0 * 256;

  f32x4 acc[2][4];
#pragma unroll
  for (int mi = 0; mi < 2; ++mi)
#pragma unroll
    for (int ni = 0; ni < 4; ++ni)
#pragma unroll
      for (int r = 0; r < 4; ++r) acc[mi][ni][r] = 0.f;

#define STAGE2(buf, t)                                                        \
  {                                                                           \
    {                                                                         \
      const int g = tid;                                                      \
      gl16(gA + (size_t)(g >> 2) * 256 + (t) * 32 + (g & 3) * 8,              \
           As2[buf] + w * 512);                                               \
    }                                                                         \
    _Pragma("unroll")                                                         \
    for (int j = 0; j < 2; ++j) {                                             \
      const int g = j * 256 + tid;                                            \
      gl16(gB + (size_t)(g >> 2) * 256 + (t) * 32 + (g & 3) * 8,              \
           Bs2[buf] + (j * 256 + w * 64) * 8);                                \
    }                                                                         \
  }

  STAGE2(0, 0);
  __syncthreads();
  const int arow = lane & 15, ag = lane >> 4;
#pragma unroll 1
  for (int t = 0; t < 8; ++t) {
    if (t < 7) STAGE2((t + 1) & 1, t + 1);
    const short* Asb = As2[t & 1];
    const short* Bsb = Bs2[t & 1];
    bf16x8 af[2], bfv[4];
#pragma unroll
    for (int mi = 0; mi < 2; ++mi)
      af[mi] = *(const bf16x8*)(Asb + (wr * 32 + mi * 16 + arow) * 32 + ag * 8);
#pragma unroll
    for (int ni = 0; ni < 4; ++ni)
      bfv[ni] = *(const bf16x8*)(Bsb + (wc * 64 + ni * 16 + arow) * 32 + ag * 8);
#pragma unroll
    for (int mi = 0; mi < 2; ++mi)
#pragma unroll
      for (int ni = 0; ni < 4; ++ni)
        acc[mi][ni] = __builtin_amdgcn_mfma_f32_16x16x32_bf16(af[mi], bfv[ni], acc[mi][ni], 0, 0, 0);
    __syncthreads();
  }
#undef STAGE2

#pragma unroll
  for (int mi = 0; mi < 2; ++mi)
#pragma unroll
    for (int ni = 0; ni < 4; ++ni) {
      const int col = n0 + wc * 64 + ni * 16 + (lane & 15);
      const float spp  = vecs[2 * 2048 + b * 256 + col];
      const float pstr = vecs[3 * 2048 + b * 256 + col];
      const float gst  = vecs[4 * 2048 + b * 256 + col];
#pragma unroll
      for (int r = 0; r < 4; ++r) {
        const int row = m0 + wr * 32 + mi * 16 + (lane >> 4) * 4 + r;
        const float pv = tanhf(acc[mi][ni][r] + spp);
        const float sp = bf2f(S[(size_t)row * 256 + col]);
        const float h = (sp + pstr * pv) * bf2f(G[(size_t)row * 256 + col]) * gst;
        H[(size_t)row * 256 + col] = f2bf(h);
        if ((row & 2047) == 2047) out[16777216 + b * 256 + col] = h;
      }
    }
}

// ---------------------------------------------------------------------------
// GEMM3: out[16384][1024] f32 = H @ wout^T. 64x256 tile, K=256 -> 8 k-steps.
// grid = 256 m x 4 n = 1024 blocks (4/CU). Wave = 32r x 128c (acc[2][8]).
__global__ __launch_bounds__(256) void gemm3_k(const short* __restrict__ H,
                                               const short* __restrict__ Wout,
                                               float* __restrict__ out) {
  __shared__ short As3[2][2048];   // [64][32]
  __shared__ short Bs3[2][8192];   // [256][32]
  const int tid = (int)threadIdx.x, lane = tid & 63, w = tid >> 6;
  const int wr = w >> 1, wc = w & 1;
  int bid = (int)blockIdx.x;
  bid = (bid & 7) * 128 + (bid >> 3);          // XCD swizzle (1024 % 8 == 0)
  const int m0 = (bid >> 2) * 64, n0 = (bid & 3) * 256;
  const short* gA = H + (size_t)m0 * 256;
  const short* gB = Wout + (size_t)n0 * 256;

  f32x4 acc[2][8];
#pragma unroll
  for (int mi = 0; mi < 2; ++mi)
#pragma unroll
    for (int ni = 0; ni < 8; ++ni)
#pragma unroll
      for (int r = 0; r < 4; ++r) acc[mi][ni][r] = 0.f;

#define STAGE3(buf, t)                                                        \
  {                                                                           \
    {                                                                         \
      const int g = tid;                                                      \
      gl16(gA + (size_t)(g >> 2) * 256 + (t) * 32 + (g & 3) * 8,              \
           As3[buf] + w * 512);                                               \
    }                                                                         \
    _Pragma("unroll")                                                         \
    for (int j = 0; j < 4; ++j) {                                             \
      const int g = j * 256 + tid;                                            \
      gl16(gB + (size_t)(g >> 2) * 256 + (t) * 32 + (g & 3) * 8,              \
           Bs3[buf] + (j * 256 + w * 64) * 8);                                \
    }                                                                         \
  }

  STAGE3(0, 0);
  __syncthreads();
  const int arow = lane & 15, ag = lane >> 4;
#pragma unroll 1
  for (int t = 0; t < 8; ++t) {
    if (t < 7) STAGE3((t + 1) & 1, t + 1);
    const short* Asb = As3[t & 1];
    const short* Bsb = Bs3[t & 1];
    bf16x8 af[2], bfv[8];
#pragma unroll
    for (int mi = 0; mi < 2; ++mi)
      af[mi] = *(const bf16x8*)(Asb + (wr * 32 + mi * 16 + arow) * 32 + ag * 8);
#pragma unroll
    for (int ni = 0; ni < 8; ++ni)
      bfv[ni] = *(const bf16x8*)(Bsb + (wc * 128 + ni * 16 + arow) * 32 + ag * 8);
#pragma unroll
    for (int mi = 0; mi < 2; ++mi)
#pragma unroll
      for (int ni = 0; ni < 8; ++ni)
        acc[mi][ni] = __builtin_amdgcn_mfma_f32_16x16x32_bf16(af[mi], bfv[ni], acc[mi][ni], 0, 0, 0);
    __syncthreads();
  }
#undef STAGE3

#pragma unroll
  for (int mi = 0; mi < 2; ++mi)
#pragma unroll
    for (int ni = 0; ni < 8; ++ni) {
      const int col = n0 + wc * 128 + ni * 16 + (lane & 15);
#pragma unroll
      for (int r = 0; r < 4; ++r) {
        const int row = m0 + wr * 32 + mi * 16 + (lane >> 4) * 4 + r;
        out[(size_t)row * 1024 + col] = acc[mi][ni][r];
      }
    }
}

// ---------------------------------------------------------------------------
extern "C" void kernel_launch(void* const* d_in, const int* in_sizes, int n_in,
                              void* d_out, int out_size, void* d_ws, size_t ws_size,
                              hipStream_t stream) {
  (void)in_sizes; (void)n_in; (void)out_size; (void)ws_size;
  const float* x      = (const float*)d_in[0];
  const float* prev   = (const float*)d_in[1];
  const float* W_in   = (const float*)d_in[2];
  const float* W_x    = (const float*)d_in[3];
  const float* W_s    = (const float*)d_in[4];
  const float* W_out  = (const float*)d_in[5];
  const float* W_gx   = (const float*)d_in[6];
  const float* b_gx   = (const float*)d_in[7];
  const float* W_gs   = (const float*)d_in[8];
  const float* b_gs   = (const float*)d_in[9];
  const float* W_dc   = (const float*)d_in[10];
  const float* b_dc   = (const float*)d_in[11];
  const float* W_pp   = (const float*)d_in[12];
  const float* b_pp   = (const float*)d_in[13];
  const float* W_pg   = (const float*)d_in[14];
  const float* b_pg   = (const float*)d_in[15];

  char* ws = (char*)d_ws;
  short* S    = (short*)(ws + OFF_S);
  short* G    = (short*)(ws + OFF_G);
  short* H    = (short*)(ws + OFF_H);
  short* wcat = (short*)(ws + OFF_WCAT);
  short* wpp  = (short*)(ws + OFF_WPP);
  short* wout = (short*)(ws + OFF_WOUT);
  float* vecs = (float*)(ws + OFF_VEC);
  float* out  = (float*)d_out;

  prep_ws_k<<<4512, 256, 0, stream>>>(W_in, W_x, W_gx, W_dc, W_pp, W_out,
                                      wcat, wpp, wout, prev, W_s, b_dc, b_pp,
                                      W_pg, b_pg, W_gs, b_gs, vecs);
  gemm1sg_k<<<512, 512, 0, stream>>>(x, wcat, prev, b_gx, vecs, S, G);
  gemm2h_k<<<512, 256, 0, stream>>>(S, G, wpp, vecs, H, out);
  gemm3_k<<<1024, 256, 0, stream>>>(H, wout, out);
}